// Round 1
// baseline (144.825 us; speedup 1.0000x reference)
//
#include <hip/hip_runtime.h>

// out[b][o] = sum_d W[labels[b]][o][d] * vad[b][d]
// B=131072, OUT_DIM=768, IN_DIM=3, NUM_CLASSES=10, all fp32.
// Pure streaming-write-bound: 402.7 MB output vs ~2.2 MB inputs.

#define NUM_B 131072
#define OUT_DIM 768
#define QUADS_PER_SAMPLE (OUT_DIM / 4)              // 192 float4 stores per sample
#define TOTAL_QUADS (NUM_B * QUADS_PER_SAMPLE)      // 25,165,824

__global__ __launch_bounds__(256) void vad_proj_kernel(
    const float* __restrict__ vad,     // (B, 3)
    const int*   __restrict__ labels,  // (B,)
    const float* __restrict__ W,       // (10, 768, 3)
    float*       __restrict__ out)     // (B, 768)
{
    const int stride = gridDim.x * blockDim.x;
    for (int i = blockIdx.x * blockDim.x + threadIdx.x; i < TOTAL_QUADS; i += stride) {
        const int b = i / QUADS_PER_SAMPLE;          // constant divide -> magic mul
        const int q = i - b * QUADS_PER_SAMPLE;      // quad index within sample

        const int l = labels[b];                     // L1-broadcast across the 192 threads/sample
        const float* vb = vad + (size_t)b * 3;
        const float v0 = vb[0], v1 = vb[1], v2 = vb[2];

        // W[l] row-major (768,3): outputs 4q..4q+3 need floats [12q, 12q+12) of W[l]
        // l*9216B and q*48B are both 16B-aligned -> 3 aligned float4 loads (L2-hot, W=92KB total)
        const float4* wp = (const float4*)(W + (size_t)l * OUT_DIM * 3) + (size_t)q * 3;
        const float4 w0 = wp[0];
        const float4 w1 = wp[1];
        const float4 w2 = wp[2];

        float4 o;
        o.x = w0.x * v0 + w0.y * v1 + w0.z * v2;
        o.y = w0.w * v0 + w1.x * v1 + w1.y * v2;
        o.z = w1.z * v0 + w1.w * v1 + w2.x * v2;
        o.w = w2.y * v0 + w2.z * v1 + w2.w * v2;

        // flat quad index == b*192 + q == i -> perfectly coalesced float4 store
        reinterpret_cast<float4*>(out)[i] = o;
    }
}

extern "C" void kernel_launch(void* const* d_in, const int* in_sizes, int n_in,
                              void* d_out, int out_size, void* d_ws, size_t ws_size,
                              hipStream_t stream) {
    const float* vad    = (const float*)d_in[0];
    const int*   labels = (const int*)d_in[1];
    const float* W      = (const float*)d_in[2];
    float*       out    = (float*)d_out;

    // Full-chip residency (256 CU x 2048 threads) + grid-stride (~48 iters/thread)
    const int block = 256;
    const int grid  = 2048;
    vad_proj_kernel<<<grid, block, 0, stream>>>(vad, labels, W, out);
}

// Round 2
// 84.476 us; speedup vs baseline: 1.7144x; 1.7144x over previous
//
#include <hip/hip_runtime.h>

// out[b][o] = sum_d W[labels[b]][o][d] * vad[b][d]
// B=131072, OUT_DIM=768, IN_DIM=3, NUM_CLASSES=10, all fp32.
// Streaming-write-bound: 402.7 MB output. Strategy: one wave per sample so
// labels/vad become wave-uniform SCALAR loads (off the VMEM latency chain),
// and each lane owns 3 independent quad chains (ILP x3).

#define B_TOTAL 131072
#define OUT_DIM 768

__global__ __launch_bounds__(256) void vad_proj_kernel(
    const float* __restrict__ vad,     // (B, 3)
    const int*   __restrict__ labels,  // (B,)
    const float* __restrict__ W,       // (10, 768, 3)
    float*       __restrict__ out)     // (B, 768)
{
    const int lane = threadIdx.x & 63;
    // wave-uniform wave index -> SGPR, so b is uniform and labels[b]/vad[b]
    // compile to scalar loads (s_load), removing one VMEM hop from the chain.
    const int wave_in_block = __builtin_amdgcn_readfirstlane((int)(threadIdx.x >> 6));
    const int waves_per_block = blockDim.x >> 6;                 // 4
    const int nwaves = gridDim.x * waves_per_block;              // 8192
    int b = blockIdx.x * waves_per_block + wave_in_block;

    #pragma unroll 2
    for (; b < B_TOTAL; b += nwaves) {                           // exactly 16 iters/wave
        const int l = labels[b];                                 // scalar load
        const float* vb = vad + (size_t)b * 3;
        const float v0 = vb[0], v1 = vb[1], v2 = vb[2];          // scalar loads

        const float4* wbase = (const float4*)(W + (size_t)l * (OUT_DIM * 3));
        float4* obase = (float4*)(out + (size_t)b * OUT_DIM);

        // lane handles quads lane, lane+64, lane+128: three independent
        // load->fma->store chains; each wave-store is 1KB contiguous.
        #pragma unroll
        for (int k = 0; k < 3; ++k) {
            const int q = lane + 64 * k;
            const float4 w0 = wbase[q * 3 + 0];
            const float4 w1 = wbase[q * 3 + 1];
            const float4 w2 = wbase[q * 3 + 2];
            float4 o;
            o.x = w0.x * v0 + w0.y * v1 + w0.z * v2;
            o.y = w0.w * v0 + w1.x * v1 + w1.y * v2;
            o.z = w1.z * v0 + w1.w * v1 + w2.x * v2;
            o.w = w2.y * v0 + w2.z * v1 + w2.w * v2;
            obase[q] = o;
        }
    }
}

extern "C" void kernel_launch(void* const* d_in, const int* in_sizes, int n_in,
                              void* d_out, int out_size, void* d_ws, size_t ws_size,
                              hipStream_t stream) {
    const float* vad    = (const float*)d_in[0];
    const int*   labels = (const int*)d_in[1];
    const float* W      = (const float*)d_in[2];
    float*       out    = (float*)d_out;

    // 2048 blocks x 4 waves = 8192 waves; 131072 samples / 8192 = 16 per wave, no tail.
    vad_proj_kernel<<<2048, 256, 0, stream>>>(vad, labels, W, out);
}